// Round 8
// baseline (483.350 us; speedup 1.0000x reference)
//
#include <hip/hip_runtime.h>
#include <hip/hip_cooperative_groups.h>
#include <math.h>

namespace cg = cooperative_groups;

#define C_HUB 1.345f

// ---------------- DPP helpers (VALU-pipe cross-lane) ----
template<int CTRL, bool BC>
__device__ __forceinline__ float fdpp(float old_, float src) {
    return __int_as_float(__builtin_amdgcn_update_dpp(
        __float_as_int(old_), __float_as_int(src), CTRL, 0xf, 0xf, BC));
}
// wave64 sum; result valid at lane 63 only
__device__ __forceinline__ float wsum63(float v) {
    v += fdpp<0x111, true>(0.f, v);   // row_shr:1
    v += fdpp<0x112, true>(0.f, v);   // row_shr:2
    v += fdpp<0x114, true>(0.f, v);   // row_shr:4
    v += fdpp<0x118, true>(0.f, v);   // row_shr:8
    v += fdpp<0x142, true>(0.f, v);   // row_bcast:15
    v += fdpp<0x143, true>(0.f, v);   // row_bcast:31
    return v;
}
template<int CTRL>
__device__ __forceinline__ unsigned udpp_keep(unsigned v) {
    return (unsigned)__builtin_amdgcn_update_dpp((int)v, (int)v, CTRL, 0xf, 0xf, false);
}
__device__ __forceinline__ unsigned wmin63(unsigned v) {
    v = min(v, udpp_keep<0x111>(v));
    v = min(v, udpp_keep<0x112>(v));
    v = min(v, udpp_keep<0x114>(v));
    v = min(v, udpp_keep<0x118>(v));
    v = min(v, udpp_keep<0x142>(v));
    v = min(v, udpp_keep<0x143>(v));
    return v;
}
__device__ __forceinline__ float bcast63(float v) {
    return __int_as_float(__builtin_amdgcn_readlane(__float_as_int(v), 63));
}

// monotone f32 <-> u32 key maps
__device__ __forceinline__ unsigned f2k(float f) {
    unsigned b = __float_as_uint(f);
    return (b & 0x80000000u) ? ~b : (b | 0x80000000u);
}
__device__ __forceinline__ float k2f(unsigned k) {
    return __uint_as_float((k & 0x80000000u) ? (k ^ 0x80000000u) : ~k);
}

// n-th smallest (1-indexed) of 1024 keys (16/lane), wave-synchronous
__device__ __forceinline__ unsigned wave_sel(const unsigned k[16], int n) {
    unsigned hi = 0u;
    for (int b = 31; b >= 0; --b) {
        unsigned pat = hi >> b;
        int cnt = 0;
        #pragma unroll
        for (int v = 0; v < 16; ++v)
            cnt += __popcll(__ballot((k[v] >> b) == pat));
        if (n > cnt) { hi |= (1u << b); n -= cnt; }
    }
    return hi;
}
// exact median (mean of middle two) of the 1024 keys
__device__ __forceinline__ float wave_median(const unsigned k[16]) {
    unsigned k1 = wave_sel(k, 512);
    int cle = 0;
    #pragma unroll
    for (int v = 0; v < 16; ++v) cle += __popcll(__ballot(k[v] <= k1));
    unsigned k2 = k1;
    if (cle < 513) {
        unsigned mg = 0xFFFFFFFFu;
        #pragma unroll
        for (int v = 0; v < 16; ++v) if (k[v] > k1) mg = min(mg, k[v]);
        mg = wmin63(mg);
        k2 = (unsigned)__builtin_amdgcn_readlane((int)mg, 63);
    }
    return 0.5f * (k2f(k1) + k2f(k2));
}

// ---------------- shared memory layout ----------------
struct SmAll {
    float rp[2][1024];
    float beta[32][2];
    float g[32][35];      // g[e][1+c] = Ginv[e][c]; cols 0,33 zero guards
    float z[2][3][32];
    float kern[2][9];
    float part[4][2];
    float scale[2];
};                        // 3452 floats
#define SM_FLOATS 3456    // 13824 B

// ---------------------------------------------------------------------------
// Transpose: block b does X-tiles 2b, 2b+1; blocks 0..31 also emit UT column b
// ---------------------------------------------------------------------------
__device__ __forceinline__ void transpose_tiles(float* sm, const float* __restrict__ X,
                                                float* __restrict__ XT,
                                                const float* __restrict__ U,
                                                float* __restrict__ UT, int b) {
    const int tid = threadIdx.x;
    const int tx = tid & 31, ty = tid >> 5;     // 32 x 8
    #pragma unroll 1
    for (int s = 0; s < 2; ++s) {
        const int tile = (b << 1) + s;
        const int bx = tile & 31, by = tile >> 5;
        __syncthreads();
        for (int dy = ty; dy < 32; dy += 8)
            sm[dy * 33 + tx] = X[(by * 32 + dy) * 1024 + bx * 32 + tx];
        __syncthreads();
        for (int dy = ty; dy < 32; dy += 8)
            XT[(bx * 32 + dy) * 1024 + by * 32 + tx] = sm[tx * 33 + dy];
    }
    if (b < 32) {
        for (int m = tid; m < 1024; m += 256)
            UT[(b << 10) + m] = U[m * 32 + b];
    }
}

// ---------------------------------------------------------------------------
// One-wave register Gauss-Jordan of the 32x32 SPD matrix staged in sm[0..1023]
// ---------------------------------------------------------------------------
__device__ __forceinline__ void gj_inv_from_sm(const float* sm, float* __restrict__ Ginv) {
    const int tid = threadIdx.x;
    if (tid < 64) {
        float col[32];
        if (tid < 32) {
            #pragma unroll
            for (int r = 0; r < 32; ++r) col[r] = sm[(r << 5) + tid];
        } else {
            #pragma unroll
            for (int r = 0; r < 32; ++r) col[r] = (tid - 32 == r) ? 1.f : 0.f;
        }
        #pragma unroll
        for (int k = 0; k < 32; ++k) {
            float piv = __shfl(col[k], k, 64);
            float pr = 1.0f / piv;
            col[k] *= pr;
            #pragma unroll
            for (int r = 0; r < 32; ++r) {
                if (r == k) continue;
                float f = __shfl(col[r], k, 64);
                col[r] -= f * col[k];
            }
        }
        if (tid >= 32) {
            #pragma unroll
            for (int r = 0; r < 32; ++r) Ginv[(r << 5) + (tid - 32)] = col[r];
        }
    }
}

// ---------------------------------------------------------------------------
// Single-block Gram+inverse from U (1024x32 row-major): G = U^T U, Ginv out
// ---------------------------------------------------------------------------
__device__ __forceinline__ void gram_inv_U(float* sm, const float* __restrict__ U,
                                           float* __restrict__ Ginv) {
    const int tid = threadIdx.x;
    float acc[4] = {0.f, 0.f, 0.f, 0.f};
    #pragma unroll 1
    for (int ch = 0; ch < 32; ++ch) {
        __syncthreads();
        #pragma unroll
        for (int s = 0; s < 4; ++s) {
            int e = tid + (s << 8);
            int kk = e >> 5, c = e & 31;
            sm[kk * 33 + c] = U[((ch << 5) + kk) * 32 + c];
        }
        __syncthreads();
        #pragma unroll
        for (int s = 0; s < 4; ++s) {
            int e = tid + (s << 8);
            int c1 = e >> 5, c2 = e & 31;
            float a = 0.f;
            #pragma unroll 8
            for (int kk = 0; kk < 32; ++kk)
                a += sm[kk * 33 + c1] * sm[kk * 33 + c2];
            acc[s] += a;
        }
    }
    __syncthreads();
    #pragma unroll
    for (int s = 0; s < 4; ++s) sm[tid + (s << 8)] = acc[s];
    __syncthreads();
    gj_inv_from_sm(sm, Ginv);
}

// ---------------------------------------------------------------------------
// Single-block Gram+inverse from AT (32x1024 row-major): G = AT AT^T
// ---------------------------------------------------------------------------
__device__ __forceinline__ void gram_inv_AT(float* sm, const float* __restrict__ AT,
                                            float* __restrict__ Ginv) {
    const int tid = threadIdx.x;
    float acc[4] = {0.f, 0.f, 0.f, 0.f};
    #pragma unroll 1
    for (int ch = 0; ch < 32; ++ch) {
        __syncthreads();
        #pragma unroll
        for (int s = 0; s < 4; ++s) {
            int e = tid + (s << 8);
            int c = e >> 5, i = e & 31;
            sm[c * 33 + i] = AT[(c << 10) + (ch << 5) + i];
        }
        __syncthreads();
        #pragma unroll
        for (int s = 0; s < 4; ++s) {
            int e = tid + (s << 8);
            int c1 = e >> 5, c2 = e & 31;
            float a = 0.f;
            #pragma unroll 8
            for (int i = 0; i < 32; ++i)
                a += sm[c1 * 33 + i] * sm[c2 * 33 + i];
            acc[s] += a;
        }
    }
    __syncthreads();
    #pragma unroll
    for (int s = 0; s < 4; ++s) sm[tid + (s << 8)] = acc[s];
    __syncthreads();
    gj_inv_from_sm(sm, Ginv);
}

// ---------------------------------------------------------------------------
// IRLS, 2 tasks (j = 2*b2, 2*b2+1), 256 threads — R6 body verbatim.
// unroll 8 (matvec) / unroll 2 (z kk-loop) cap in-flight loads (R5 spill fix).
// ---------------------------------------------------------------------------
__device__ __forceinline__ void irls2_block(
    float* smraw, int b2, const float* __restrict__ Yr, const float* __restrict__ A32,
    const float* __restrict__ GinvG, const float* __restrict__ kb,
    const float* __restrict__ bsrc, float* __restrict__ vnew,
    float* __restrict__ out, int phase)
{
    SmAll& S = *reinterpret_cast<SmAll*>(smraw);
    const int tid = threadIdx.x;
    const int lane = tid & 63, wv_id = tid >> 6;
    const float4* Y4 = (const float4*)Yr;
    const float4* A4 = (const float4*)A32;

    __syncthreads();   // guard vs. prior phase's sm use
    for (int i = tid; i < 1024; i += 256) {
        int e = i >> 5, c = i & 31;
        S.g[e][1 + c] = GinvG[i];
    }
    if (tid < 32) S.g[tid][0] = 0.f;
    else if (tid < 64) S.g[tid - 32][33] = 0.f;
    if (tid >= 64 && tid < 128) {
        int e = tid - 64, t = e >> 5, c = e & 31, j = (b2 << 1) + t;
        S.beta[c][t] = (phase == 0) ? bsrc[(c << 10) + j] : bsrc[j * 32 + c];
    }
    if (tid >= 192 && tid < 210) {
        int e = tid - 192, t = e / 9, r = e % 9, j = (b2 << 1) + t;
        S.kern[t][r] = (phase == 0) ? kb[j * 9 + r] : kb[j * 9 + (r % 3) * 3 + (r / 3)];
    }
    __syncthreads();

    auto matvec = [&](float4* r) {
        r[0] = Y4[(((b2 << 1) + 0) << 8) + tid];
        r[1] = Y4[(((b2 << 1) + 1) << 8) + tid];
        #pragma unroll 8
        for (int c = 0; c < 32; ++c) {
            float2 bb = *((const float2*)S.beta[c]);
            float4 a = A4[(c << 8) + tid];
            r[0].x -= a.x * bb.x; r[0].y -= a.y * bb.x; r[0].z -= a.z * bb.x; r[0].w -= a.w * bb.x;
            r[1].x -= a.x * bb.y; r[1].y -= a.y * bb.y; r[1].z -= a.z * bb.y; r[1].w -= a.w * bb.y;
        }
    };

    float4 r[2];
    matvec(r);
    #pragma unroll
    for (int t = 0; t < 2; ++t) ((float4*)S.rp[t])[tid] = r[t];
    __syncthreads();

    // per-wave exact medians -> initial scale (waves 0,1)
    if (wv_id < 2) {
        float fv[16]; unsigned kk[16];
        #pragma unroll
        for (int v = 0; v < 16; ++v) fv[v] = S.rp[wv_id][lane + (v << 6)];
        #pragma unroll
        for (int v = 0; v < 16; ++v) kk[v] = f2k(fv[v]);
        float med = wave_median(kk);
        #pragma unroll
        for (int v = 0; v < 16; ++v) kk[v] = f2k(fabsf(fv[v] - med));
        float mad = wave_median(kk);
        if (lane == 0) S.scale[wv_id] = 1.4815f * mad;
    }
    __syncthreads();

    float scale[2];
    #pragma unroll
    for (int t = 0; t < 2; ++t) scale[t] = S.scale[t];

    const float inv_denom = 1.0f / (2.0f * 0.7102f * (1024.0f - 32.0f - 1.0f));
    const float C2 = C_HUB * C_HUB;

    for (int it = 0; it < 3; ++it) {
        matvec(r);

        #pragma unroll
        for (int t = 0; t < 2; ++t) {
            float s = scale[t];
            float u0 = r[t].x / s, u1 = r[t].y / s, u2 = r[t].z / s, u3 = r[t].w / s;
            float part = 0.5f * (fminf(u0 * u0, C2) + fminf(u1 * u1, C2) +
                                 fminf(u2 * u2, C2) + fminf(u3 * u3, C2));
            float ps = wsum63(part);
            if (lane == 63) S.part[wv_id][t] = ps;
        }
        __syncthreads();

        #pragma unroll
        for (int t = 0; t < 2; ++t) {
            float ss = S.part[0][t] + S.part[1][t] + S.part[2][t] + S.part[3][t];
            float s = sqrtf(2.0f * scale[t] * scale[t] * inv_denom * ss);
            scale[t] = s;
            float4 rp;
            rp.x = fminf(fmaxf(r[t].x / s, -C_HUB), C_HUB) * s;
            rp.y = fminf(fmaxf(r[t].y / s, -C_HUB), C_HUB) * s;
            rp.z = fminf(fmaxf(r[t].z / s, -C_HUB), C_HUB) * s;
            rp.w = fminf(fmaxf(r[t].w / s, -C_HUB), C_HUB) * s;
            ((float4*)S.rp[t])[tid] = rp;
        }
        __syncthreads();

        // z[q][e] = sum_k A32[e][k] * rp[k+1-q]  (shifts applied to A via lanes)
        #pragma unroll 1
        for (int half = 0; half < 2; ++half) {
            float a0[4][2], a1[4][2], a2[4][2];
            #pragma unroll
            for (int cc = 0; cc < 4; ++cc)
                #pragma unroll
                for (int t = 0; t < 2; ++t) { a0[cc][t] = 0.f; a1[cc][t] = 0.f; a2[cc][t] = 0.f; }
            float wlast[4] = {0.f, 0.f, 0.f, 0.f};
            float rplast[2] = {0.f, 0.f};
            #pragma unroll 2
            for (int kk = 0; kk < 4; ++kk) {
                float4 rp4[2]; float rpl_new[2];
                #pragma unroll
                for (int t = 0; t < 2; ++t) {
                    rp4[t] = ((const float4*)S.rp[t])[(kk << 6) + lane];
                    rpl_new[t] = bcast63(rp4[t].w);
                }
                #pragma unroll
                for (int cc = 0; cc < 4; ++cc) {
                    const int cp = (wv_id << 3) + (half << 2) + cc;
                    float4 w4 = A4[(cp << 8) + (kk << 6) + lane];
                    float wprev = __shfl_up(w4.w, 1, 64);
                    if (lane == 0) wprev = wlast[cc];
                    float wnext = __shfl_down(w4.x, 1, 64);
                    if (lane == 63) wnext = 0.f;
                    float wcomp = (lane == 0) ? w4.x : 0.f;   // deferred chunk-edge term
                    #pragma unroll
                    for (int t = 0; t < 2; ++t) {
                        float4 rp = rp4[t];
                        a1[cc][t] += w4.x * rp.x + w4.y * rp.y + w4.z * rp.z + w4.w * rp.w;
                        a0[cc][t] += wprev * rp.x + w4.x * rp.y + w4.y * rp.z + w4.z * rp.w;
                        a2[cc][t] += w4.y * rp.x + w4.z * rp.y + w4.w * rp.z + wnext * rp.w
                                   + wcomp * rplast[t];
                    }
                    wlast[cc] = bcast63(w4.w);
                }
                #pragma unroll
                for (int t = 0; t < 2; ++t) rplast[t] = rpl_new[t];
            }
            #pragma unroll
            for (int cc = 0; cc < 4; ++cc) {
                const int cp = (wv_id << 3) + (half << 2) + cc;
                #pragma unroll
                for (int t = 0; t < 2; ++t) {
                    float z0 = wsum63(a0[cc][t]);
                    float z1 = wsum63(a1[cc][t]);
                    float z2 = wsum63(a2[cc][t]);
                    if (lane == 63) {
                        S.z[t][0][cp] = z0; S.z[t][1][cp] = z1; S.z[t][2][cp] = z2;
                    }
                }
            }
        }
        __syncthreads();

        // beta[c][t] += sum_e sum_q (sum_p kern[p][q] G[c+p-1][e]) z[q][e]
        if (tid < 64) {
            int t = tid >> 5, c = tid & 31;
            float kn[9];
            #pragma unroll
            for (int x = 0; x < 9; ++x) kn[x] = S.kern[t][x];
            float d = 0.f;
            #pragma unroll 4
            for (int e = 0; e < 32; ++e) {
                float gm = S.g[e][c];       // G[c-1][e]
                float gc = S.g[e][c + 1];   // G[c  ][e]
                float gp = S.g[e][c + 2];   // G[c+1][e]
                float z0 = S.z[t][0][e], z1 = S.z[t][1][e], z2 = S.z[t][2][e];
                d += (kn[0] * gm + kn[3] * gc + kn[6] * gp) * z0
                   + (kn[1] * gm + kn[4] * gc + kn[7] * gp) * z1
                   + (kn[2] * gm + kn[5] * gc + kn[8] * gp) * z2;
            }
            S.beta[c][t] += d;
        }
        __syncthreads();
    }

    if (tid < 64) {
        int t = tid >> 5, c = tid & 31, j = (b2 << 1) + t;
        float bv = S.beta[c][t];
        if (phase == 0) {
            vnew[(c << 10) + j] = bv;
            out[c * 2048 + 1024 + j] = bv;
        } else {
            out[c * 2048 + j] = bv;
        }
    }
}

// ---------------------------------------------------------------------------
// Mega kernel: whole DAG, 512 blocks (2 blocks/CU — large co-residency margin)
// ---------------------------------------------------------------------------
__global__ __launch_bounds__(256, 2) void mega_kernel(
    const float* __restrict__ X, const float* __restrict__ U,
    const float* __restrict__ V, const float* __restrict__ CK,
    float* __restrict__ out, float* __restrict__ XT, float* __restrict__ UT,
    float* __restrict__ Vn, float* __restrict__ Ginv)
{
    __shared__ __align__(16) float sm[SM_FLOATS];
    cg::grid_group grid = cg::this_grid();
    const int b = blockIdx.x;

    transpose_tiles(sm, X, XT, U, UT, b);
    if (b == 0) gram_inv_U(sm, U, Ginv);
    grid.sync();

    irls2_block(sm, b, XT, UT, Ginv, CK, V, Vn, out, 0);
    grid.sync();

    if (b == 0) gram_inv_AT(sm, Vn, Ginv);
    grid.sync();

    irls2_block(sm, b, X, Vn, Ginv, CK + 1023 * 9, U, nullptr, out, 1);
}

// ---------------------------------------------------------------------------
// Fallback split kernels (used only if cooperative launch is rejected)
// ---------------------------------------------------------------------------
__global__ __launch_bounds__(256) void transpose512_kernel(
    const float* __restrict__ X, float* __restrict__ XT,
    const float* __restrict__ U, float* __restrict__ UT) {
    __shared__ __align__(16) float sm[1056];
    transpose_tiles(sm, X, XT, U, UT, blockIdx.x);
}
__global__ __launch_bounds__(256) void graminvU_kernel(const float* __restrict__ U,
                                                       float* __restrict__ Ginv) {
    __shared__ __align__(16) float sm[1056];
    gram_inv_U(sm, U, Ginv);
}
__global__ __launch_bounds__(256) void graminvAT_kernel(const float* __restrict__ AT,
                                                        float* __restrict__ Ginv) {
    __shared__ __align__(16) float sm[1056];
    gram_inv_AT(sm, AT, Ginv);
}
__global__ __launch_bounds__(256, 2) void irls2_kernel(
    const float* __restrict__ Yr, const float* __restrict__ A32,
    const float* __restrict__ Ginv, const float* __restrict__ kb,
    const float* __restrict__ bsrc, float* __restrict__ vnew,
    float* __restrict__ out, int phase) {
    __shared__ __align__(16) float sm[SM_FLOATS];
    irls2_block(sm, blockIdx.x, Yr, A32, Ginv, kb, bsrc, vnew, out, phase);
}

// ---------------------------------------------------------------------------
extern "C" void kernel_launch(void* const* d_in, const int* in_sizes, int n_in,
                              void* d_out, int out_size, void* d_ws, size_t ws_size,
                              hipStream_t stream) {
    const float* X  = (const float*)d_in[0];
    const float* U  = (const float*)d_in[1];
    const float* V  = (const float*)d_in[2];
    const float* CK = (const float*)d_in[3];
    float* out = (float*)d_out;

    float* f    = (float*)d_ws;
    float* XT   = f;                    // 1024*1024
    float* UT   = f + (1 << 20);        // 32*1024
    float* Vn   = UT + 32768;           // 32*1024
    float* Ginv = Vn + 32768;           // 1024

    void* args[] = {(void*)&X, (void*)&U, (void*)&V, (void*)&CK, (void*)&out,
                    (void*)&XT, (void*)&UT, (void*)&Vn, (void*)&Ginv};
    hipError_t err = hipLaunchCooperativeKernel((const void*)mega_kernel,
                                                dim3(512), dim3(256), args, 0, stream);
    if (err != hipSuccess) {
        (void)hipGetLastError();   // clear sticky error, take split path
        transpose512_kernel<<<512, 256, 0, stream>>>(X, XT, U, UT);
        graminvU_kernel<<<1, 256, 0, stream>>>(U, Ginv);
        irls2_kernel<<<512, 256, 0, stream>>>(XT, UT, Ginv, CK, V, Vn, out, 0);
        graminvAT_kernel<<<1, 256, 0, stream>>>(Vn, Ginv);
        irls2_kernel<<<512, 256, 0, stream>>>(X, Vn, Ginv, CK + 1023 * 9, U, nullptr, out, 1);
    }
}